// Round 6
// baseline (123.441 us; speedup 1.0000x reference)
//
#include <hip/hip_runtime.h>

// Per-token head-attention: B*S tokens, each: S = Q K^T/sqrt(128) (32x32 over
// heads), P = softmax over heads, O = P V (32x128). One wave = one token round;
// persistent waves, kTPW sequential tokens each (long linear DRAM streams).
// ALL global reads are 1KB-contiguous global_load_lds; LDS is XOR-swizzled via
// pre-swizzled per-lane SOURCE addresses (rule 21) so fragment ds_read_b128 is
// ~conflict-free. Counted vmcnt keeps next-token stages in flight (T4).

typedef __bf16 bf16x8 __attribute__((ext_vector_type(8)));
typedef __bf16 bf16x2 __attribute__((ext_vector_type(2)));
typedef float  f32x4  __attribute__((ext_vector_type(4)));

static constexpr float kScale = 0.08838834764831845f;  // 1/sqrt(128)
static constexpr int kTPW = 8;                          // tokens per wave

typedef const __attribute__((address_space(1))) unsigned int* gas_ptr;
typedef __attribute__((address_space(3))) unsigned int* las_ptr;

#define WAITV16() asm volatile("s_waitcnt vmcnt(16)" ::: "memory")
#define WAITV32() asm volatile("s_waitcnt vmcnt(32)" ::: "memory")
#define WAITV0()  asm volatile("s_waitcnt vmcnt(0)"  ::: "memory")
#define WAITL0()  asm volatile("s_waitcnt lgkmcnt(0)" ::: "memory")
#define SBAR()    __builtin_amdgcn_sched_barrier(0)

__device__ inline bf16x8 to_bf16x8(f32x4 a, f32x4 b) {
  bf16x8 f;
  f[0] = (__bf16)a[0]; f[1] = (__bf16)a[1];
  f[2] = (__bf16)a[2]; f[3] = (__bf16)a[3];
  f[4] = (__bf16)b[0]; f[5] = (__bf16)b[1];
  f[6] = (__bf16)b[2]; f[7] = (__bf16)b[3];
  return f;
}

__global__ __launch_bounds__(64) void attn_headwise(
    const float* __restrict__ q, const float* __restrict__ k,
    const float* __restrict__ v, float* __restrict__ out, int ntok) {
  const int lane = threadIdx.x;        // one wave per block
  const int lr   = lane & 15;
  const int G    = lane >> 4;
  const long base = (long)blockIdx.x * kTPW;
  if (base >= ntok) return;

  // Swizzled f32 token tiles: [32 rows][128 floats]; 16B chunk c of row r
  // holds global chunk c ^ (r&7).  50.5 KB total -> 3 blocks/CU.
  __shared__ __align__(16) float        qls[32 * 128];
  __shared__ __align__(16) float        kls[32 * 128];
  __shared__ __align__(16) float        vls[32 * 128];
  __shared__ __align__(16) unsigned int pbuf[32 * 20];

  // per-lane swizzled source offsets (period 4 in instruction index)
  int soff[4];
  {
    const int b = lane >> 5;
    #pragma unroll
    for (int j = 0; j < 4; ++j)
      soff[j] = b * 128 + 4 * ((lane & 31) ^ (((2 * j) & 7) + b));
  }
  auto stage = [&](const float* tokbase, float* dst) {  // 16 x 1KB contiguous
    #pragma unroll
    for (int i = 0; i < 16; ++i)
      __builtin_amdgcn_global_load_lds((gas_ptr)(tokbase + i * 256 + soff[i & 3]),
                                       (las_ptr)(dst + i * 256), 16, 0, 0);
  };
  // MFMA A/B fragment from swizzled f32 tile: rows 16*tt+lr, floats [32kk+8G,+8)
  auto frag = [&](const float* ls, int kk, int tt) -> bf16x8 {
    const int row = 16 * tt + lr;
    const int c0  = 8 * kk + 2 * G;
    f32x4 a = *(const f32x4*)&ls[row * 128 + 4 * ((c0)     ^ (row & 7))];
    f32x4 b = *(const f32x4*)&ls[row * 128 + 4 * ((c0 + 1) ^ (row & 7))];
    return to_bf16x8(a, b);
  };

  // prologue: token base fully staged (QK first, then V) -> 48 in flight
  stage(k + base * 4096, kls);
  stage(q + base * 4096, qls);
  stage(v + base * 4096, vls);

  #pragma unroll 1
  for (int it = 0; it < kTPW; ++it) {
    const long tok = base + it;
    float* ot = out + tok * 4096;

    // a) QK(t) landed. steady entry (oldest->newest): QK(t)32, stores(t-1)16,
    //    V(t)16 -> vmcnt(32). it==0: QK32,V16 -> vmcnt(16).
    if (it == 0) { WAITV16(); } else { WAITV32(); }
    SBAR();

    // b) QK fragments from LDS (swizzled b128) + cvt to bf16
    bf16x8 kf[4][2], qf[4][2];
    #pragma unroll
    for (int kk = 0; kk < 4; ++kk)
      #pragma unroll
      for (int tt = 0; tt < 2; ++tt) {
        kf[kk][tt] = frag(kls, kk, tt);
        qf[kk][tt] = frag(qls, kk, tt);
      }
    WAITL0();   // frag reads retired -> QK LDS regions safe to overwrite
    SBAR();

    // c) issue next token's QK stages (32 x 1KB, stay in flight across compute)
    if (it + 1 < kTPW) {
      stage(k + (tok + 1) * 4096, kls);
      stage(q + (tok + 1) * 4096, qls);
    }
    SBAR();

    // d) S^T[g][h] = sum_d K[g][d] Q[h][d]
    f32x4 acc[2][2];
    acc[0][0] = 0.f; acc[0][1] = 0.f; acc[1][0] = 0.f; acc[1][1] = 0.f;
    #pragma unroll
    for (int kk = 0; kk < 4; ++kk)
      #pragma unroll
      for (int gi = 0; gi < 2; ++gi)
        #pragma unroll
        for (int hj = 0; hj < 2; ++hj)
          acc[gi][hj] = __builtin_amdgcn_mfma_f32_16x16x32_bf16(
              kf[kk][gi], qf[kk][hj], acc[gi][hj], 0, 0, 0);

    // softmax over g (rows of S^T), per column h; normalized P -> LDS (bf16)
    #pragma unroll
    for (int hj = 0; hj < 2; ++hj) {
      float m = acc[0][hj][0];
      #pragma unroll
      for (int gi = 0; gi < 2; ++gi)
        #pragma unroll
        for (int r = 0; r < 4; ++r) m = fmaxf(m, acc[gi][hj][r]);
      m = fmaxf(m, __shfl_xor(m, 16, 64));
      m = fmaxf(m, __shfl_xor(m, 32, 64));

      float pv[2][4];
      float s = 0.f;
      #pragma unroll
      for (int gi = 0; gi < 2; ++gi)
        #pragma unroll
        for (int r = 0; r < 4; ++r) {
          float e = __expf((acc[gi][hj][r] - m) * kScale);
          pv[gi][r] = e;
          s += e;
        }
      s += __shfl_xor(s, 16, 64);
      s += __shfl_xor(s, 32, 64);
      float inv = 1.0f / s;

      #pragma unroll
      for (int gi = 0; gi < 2; ++gi)
        #pragma unroll
        for (int mp = 0; mp < 2; ++mp) {
          bf16x2 t2;
          t2[0] = (__bf16)(pv[gi][2 * mp]     * inv);
          t2[1] = (__bf16)(pv[gi][2 * mp + 1] * inv);
          pbuf[(16 * hj + lr) * 20 + 8 * gi + 2 * G + mp] =
              __builtin_bit_cast(unsigned int, t2);
        }
    }
    bf16x8 pf[2];
    #pragma unroll
    for (int ht = 0; ht < 2; ++ht)
      pf[ht] = *(const bf16x8*)&pbuf[(16 * ht + lr) * 20 + 4 * G];

    // e) V(t) landed. steady: drains stores(t-1)+V(t), keeps QK(t+1)=32.
    //    last iteration: drain everything.
    if (it + 1 == kTPW) { WAITV0(); } else { WAITV32(); }
    SBAR();

    // f) PV from swizzled V tile: O^T = V^T P^T ; coalesced f32x4 stores
    f32x4 zero = 0.f;
    #pragma unroll
    for (int dt = 0; dt < 8; ++dt) {
      bf16x8 vf;
      #pragma unroll
      for (int e = 0; e < 8; ++e) {
        const int row = 8 * G + e;               // head g
        vf[e] = (__bf16)vls[row * 128 +
                            4 * ((4 * dt + (lr >> 2)) ^ (row & 7)) + (lr & 3)];
      }
      f32x4 o0 = __builtin_amdgcn_mfma_f32_16x16x32_bf16(vf, pf[0], zero, 0, 0, 0);
      f32x4 o1 = __builtin_amdgcn_mfma_f32_16x16x32_bf16(vf, pf[1], zero, 0, 0, 0);
      *(f32x4*)&ot[lr * 128 + 16 * dt + 4 * G]        = o0;
      *(f32x4*)&ot[(16 + lr) * 128 + 16 * dt + 4 * G] = o1;
    }
    WAITL0();   // V reads retired -> V LDS region safe to overwrite
    SBAR();

    // g) issue next token's V stage (lands before iter t+1's e-wait)
    if (it + 1 < kTPW) stage(v + (tok + 1) * 4096, vls);
  }
}

extern "C" void kernel_launch(void* const* d_in, const int* in_sizes, int n_in,
                              void* d_out, int out_size, void* d_ws, size_t ws_size,
                              hipStream_t stream) {
  const float* q = (const float*)d_in[0];
  const float* k = (const float*)d_in[1];
  const float* v = (const float*)d_in[2];
  float* out = (float*)d_out;
  int ntok = in_sizes[0] / 4096;                 // B*S tokens (H*D = 4096)
  int grid = (ntok + kTPW - 1) / kTPW;           // one wave per block
  hipLaunchKernelGGL(attn_headwise, dim3(grid), dim3(64), 0, stream,
                     q, k, v, out, ntok);
}

// Round 7
// 100.251 us; speedup vs baseline: 1.2313x; 1.2313x over previous
//
#include <hip/hip_runtime.h>

// Per-token head-attention: B*S = 8192 independent tokens, each does
//   S = Q K^T / sqrt(128)  (32x32 over heads), P = softmax_rows(S), O = P V.
// One wave (64 lanes) owns one token. Base structure = R1 (best so far).
// R7 change (single theory: rebalance L3 vs HBM service):
//   - output stores are non-temporal (dead lines stop evicting Q/K from L3)
//   - V loads are non-temporal (V served from HBM headroom; L3 keeps Q/K)

typedef __bf16 bf16x8 __attribute__((ext_vector_type(8)));
typedef __bf16 bf16x2 __attribute__((ext_vector_type(2)));
typedef float  f32x4  __attribute__((ext_vector_type(4)));

static constexpr float kScale = 0.08838834764831845f;  // 1/sqrt(128)

__global__ __launch_bounds__(256) void attn_headwise(
    const float* __restrict__ q, const float* __restrict__ k,
    const float* __restrict__ v, float* __restrict__ out, int ntok) {
  const int wave = threadIdx.x >> 6;
  const int lane = threadIdx.x & 63;
  const int lr   = lane & 15;   // row/col-in-tile part
  const int G    = lane >> 4;   // lane group 0..3

  const long token = (long)blockIdx.x * 4 + wave;
  if (token >= ntok) return;
  const float* qt = q + token * 4096;
  const float* kt = k + token * 4096;
  const float* vt = v + token * 4096;
  float*       ot = out + token * 4096;

  // per-wave P buffer: 32 rows (h) x 32 cols (g) bf16 = 32x16 dwords
  __shared__ __align__(16) unsigned int pbuf[4][32 * 16];
  unsigned int* pl = pbuf[wave];

  // ---------------- S^T[g][h] = sum_d K[g][d] * Q[h][d] ----------------
  f32x4 acc[2][2];
  acc[0][0] = 0.f; acc[0][1] = 0.f; acc[1][0] = 0.f; acc[1][1] = 0.f;

  #pragma unroll
  for (int kk = 0; kk < 4; ++kk) {
    bf16x8 af[2], bq[2];
    #pragma unroll
    for (int gi = 0; gi < 2; ++gi) {
      const float* p = kt + (16 * gi + lr) * 128 + 32 * kk + 8 * G;
      f32x4 u0 = *(const f32x4*)p;
      f32x4 u1 = *(const f32x4*)(p + 4);
      bf16x8 f;
      f[0] = (__bf16)u0[0]; f[1] = (__bf16)u0[1];
      f[2] = (__bf16)u0[2]; f[3] = (__bf16)u0[3];
      f[4] = (__bf16)u1[0]; f[5] = (__bf16)u1[1];
      f[6] = (__bf16)u1[2]; f[7] = (__bf16)u1[3];
      af[gi] = f;
    }
    #pragma unroll
    for (int hj = 0; hj < 2; ++hj) {
      const float* p = qt + (16 * hj + lr) * 128 + 32 * kk + 8 * G;
      f32x4 u0 = *(const f32x4*)p;
      f32x4 u1 = *(const f32x4*)(p + 4);
      bf16x8 f;
      f[0] = (__bf16)u0[0]; f[1] = (__bf16)u0[1];
      f[2] = (__bf16)u0[2]; f[3] = (__bf16)u0[3];
      f[4] = (__bf16)u1[0]; f[5] = (__bf16)u1[1];
      f[6] = (__bf16)u1[2]; f[7] = (__bf16)u1[3];
      bq[hj] = f;
    }
    #pragma unroll
    for (int gi = 0; gi < 2; ++gi)
      #pragma unroll
      for (int hj = 0; hj < 2; ++hj)
        acc[gi][hj] = __builtin_amdgcn_mfma_f32_16x16x32_bf16(
            af[gi], bq[hj], acc[gi][hj], 0, 0, 0);
  }

  // ---------------- softmax over g (rows of S^T), per column h ----------
  #pragma unroll
  for (int hj = 0; hj < 2; ++hj) {
    float m = acc[0][hj][0];
    #pragma unroll
    for (int gi = 0; gi < 2; ++gi)
      #pragma unroll
      for (int r = 0; r < 4; ++r) m = fmaxf(m, acc[gi][hj][r]);
    m = fmaxf(m, __shfl_xor(m, 16, 64));
    m = fmaxf(m, __shfl_xor(m, 32, 64));

    float pv[2][4];
    float s = 0.f;
    #pragma unroll
    for (int gi = 0; gi < 2; ++gi)
      #pragma unroll
      for (int r = 0; r < 4; ++r) {
        float e = __expf((acc[gi][hj][r] - m) * kScale);
        pv[gi][r] = e;
        s += e;
      }
    s += __shfl_xor(s, 16, 64);
    s += __shfl_xor(s, 32, 64);
    float inv = 1.0f / s;

    #pragma unroll
    for (int gi = 0; gi < 2; ++gi)
      #pragma unroll
      for (int mp = 0; mp < 2; ++mp) {
        bf16x2 t;
        t[0] = (__bf16)(pv[gi][2 * mp]     * inv);
        t[1] = (__bf16)(pv[gi][2 * mp + 1] * inv);
        pl[(16 * hj + lr) * 16 + 8 * gi + 2 * G + mp] =
            __builtin_bit_cast(unsigned int, t);
      }
  }

  // ---------------- read P fragments (B-operand) -------------------------
  bf16x8 pf[2];
  #pragma unroll
  for (int ht = 0; ht < 2; ++ht)
    pf[ht] = *(const bf16x8*)&pl[(16 * ht + lr) * 16 + 4 * G];

  // ---------------- O^T = V^T * P^T  (V loads non-temporal) --------------
  f32x4 zero = 0.f;
  #pragma unroll
  for (int dt = 0; dt < 8; ++dt) {
    const float* vp = vt + 8 * G * 128 + 16 * dt + lr;
    bf16x8 vf;
    #pragma unroll
    for (int e = 0; e < 8; ++e)
      vf[e] = (__bf16)__builtin_nontemporal_load(vp + e * 128);
    f32x4 o0 = __builtin_amdgcn_mfma_f32_16x16x32_bf16(vf, pf[0], zero, 0, 0, 0);
    f32x4 o1 = __builtin_amdgcn_mfma_f32_16x16x32_bf16(vf, pf[1], zero, 0, 0, 0);
    __builtin_nontemporal_store(o0, (f32x4*)&ot[lr * 128 + 16 * dt + 4 * G]);
    __builtin_nontemporal_store(o1, (f32x4*)&ot[(16 + lr) * 128 + 16 * dt + 4 * G]);
  }
}

extern "C" void kernel_launch(void* const* d_in, const int* in_sizes, int n_in,
                              void* d_out, int out_size, void* d_ws, size_t ws_size,
                              hipStream_t stream) {
  const float* q = (const float*)d_in[0];
  const float* k = (const float*)d_in[1];
  const float* v = (const float*)d_in[2];
  float* out = (float*)d_out;
  int ntok = in_sizes[0] / 4096;          // B*S tokens (H*D = 4096)
  int grid = (ntok + 3) / 4;              // 4 waves (tokens) per 256-thread block
  hipLaunchKernelGGL(attn_headwise, dim3(grid), dim3(256), 0, stream,
                     q, k, v, out, ntok);
}